// Round 13
// baseline (170.358 us; speedup 1.0000x reference)
//
#include <hip/hip_runtime.h>

#define IN_C  5
#define HID_C 128
#define OUT_C 64

#define KB   256      // nodes per bucket (dst >> 8)
#define NBP  512      // padded bucket count (== BTH, one bucket per thread in scan)
#define CAP  10240    // fixed per-bucket edge capacity (mean 8184, +22 sigma)
#define HCAP 5120     // half-bucket LDS stage (mean 4092, +16 sigma)
#define TILE 8192     // edges per k_bin block (R21: 16-edge runs = full-line stores)
#define BTH  512      // block size
#define EPT  (TILE / BTH)
#define EPTV (TILE / BTH / 4)
#define GNODES 64     // nodes per gather block (8 threads/node x 512)

// Native vector types (__builtin_nontemporal_* rejects HIP_vector_type)
typedef int      vi4 __attribute__((ext_vector_type(4)));
typedef float    vf4 __attribute__((ext_vector_type(4)));
typedef _Float16 vh8 __attribute__((ext_vector_type(8)));

// ---------------------------------------------------------------------------
// Linear-GCN folding: z = Ahat^2 X (W1 W2) + (Ahat 1)(b1 W2) + b2.
// R24 == R23 (never ran: broker failure x2). R23 = R21 (verified 166.3us;
// R22's padded-segment int4-srclist variant REVERTED: +3.6us) + k_build
// SPLIT 2 half-blocks/bucket:
//   - 391 -> 782 blocks (1.53 -> 3.05 blocks/CU; kills the grid tail where
//     135 CUs ran 2 serial blocks). Each half re-reads the bucket segment
//     (L2-hot) and counts all 256 degrees (deterministic identical totals;
//     ranks block-local + self-consistent), but sorts/flushes only its own
//     128 nodes (stage 20KB; own base = wte[2] from the existing scan).
// Gather floor (measured, 6 interventions): MSHR-bound, 0.147 miss/cy/CU
// ~= 30 MSHRs x 200cy L2 latency; only lookup COUNT moves it (R18 f16
// 1-load/edge -12.7us) and we are at 1/edge minimum.
// R21: k_bin 16-edge full-line runs -6.6us. R20: NEVER per-edge random
// global atomics (cross-XCD ping-pong, 163us). R16: nt near gathers kills
// L1 reuse. R14: divergent global scatter >> coalesced/LDS staging.
// Payload packed 4B: (dst&255)<<24 | src; payload may be NEGATIVE when
// (dst&255)>=128 — never sign-test validity (R4 bug).
// ---------------------------------------------------------------------------

// Bucket-partition a tile: LDS hist (rank-capturing) -> scan -> bucket-sorted
// LDS stage with precomputed global dests -> run-contiguous global stores.
__global__ __launch_bounds__(BTH) void k_bin(const int* __restrict__ src,
                                             const int* __restrict__ dstp,
                                             int* __restrict__ gcursor,
                                             int* __restrict__ binned, int e) {
    __shared__ int lhist[NBP];
    __shared__ int lgofs[NBP];    // (bucket global window) - (local run start)
    __shared__ int lbeg[NBP];
    __shared__ int lsort[TILE];
    __shared__ int gdst[TILE];
    __shared__ int wsum[8];
    __shared__ int stot;
    int tid = threadIdx.x;
    int lane = tid & 63, w = tid >> 6;
    int tbeg = blockIdx.x * TILE;
    lhist[tid] = 0;                            // NBP == BTH
    __syncthreads();
    int pk[EPT], bk[EPT], rk[EPT];
    #pragma unroll
    for (int q = 0; q < EPTV; ++q) {
        int idx = tbeg + (q * BTH + tid) * 4;  // e % 4 == 0: all-or-nothing
        if (idx < e) {
            vi4 s4 = __builtin_nontemporal_load((const vi4*)(src + idx));
            vi4 d4 = __builtin_nontemporal_load((const vi4*)(dstp + idx));
            pk[q*4+0] = ((d4.x & 255) << 24) | s4.x; bk[q*4+0] = ((unsigned)d4.x) >> 8;
            pk[q*4+1] = ((d4.y & 255) << 24) | s4.y; bk[q*4+1] = ((unsigned)d4.y) >> 8;
            pk[q*4+2] = ((d4.z & 255) << 24) | s4.z; bk[q*4+2] = ((unsigned)d4.z) >> 8;
            pk[q*4+3] = ((d4.w & 255) << 24) | s4.w; bk[q*4+3] = ((unsigned)d4.w) >> 8;
            rk[q*4+0] = atomicAdd(&lhist[bk[q*4+0]], 1);   // rank in bucket
            rk[q*4+1] = atomicAdd(&lhist[bk[q*4+1]], 1);
            rk[q*4+2] = atomicAdd(&lhist[bk[q*4+2]], 1);
            rk[q*4+3] = atomicAdd(&lhist[bk[q*4+3]], 1);
        } else {
            bk[q*4+0] = -1; bk[q*4+1] = -1; bk[q*4+2] = -1; bk[q*4+3] = -1;
        }
    }
    __syncthreads();
    // block-wide exclusive scan of 512 bucket counts (one per thread)
    int h = lhist[tid];
    int v = h;
    #pragma unroll
    for (int m = 1; m < 64; m <<= 1) { int u = __shfl_up(v, m); if (lane >= m) v += u; }
    if (lane == 63) wsum[w] = v;
    __syncthreads();
    if (tid == 0) {
        int s = 0;
        #pragma unroll
        for (int k = 0; k < 8; ++k) { int tv = wsum[k]; wsum[k] = s; s += tv; }
    }
    __syncthreads();
    int excl = wsum[w] + v - h;                // exclusive prefix for bucket tid
    lbeg[tid] = excl;
    if (h > 0)
        lgofs[tid] = tid * CAP + atomicAdd(&gcursor[tid], h) - excl;
    if (tid == BTH - 1) stot = excl + h;       // total valid edges in tile
    __syncthreads();
    #pragma unroll
    for (int q = 0; q < EPT; ++q) {
        if (bk[q] >= 0) {
            int slot = lbeg[bk[q]] + rk[q];    // no second atomic
            lsort[slot] = pk[q];
            gdst[slot] = lgofs[bk[q]] + slot;  // consecutive within a run
        }
    }
    __syncthreads();
    int tot = stot;
    for (int i = tid; i < tot; i += BTH)
        binned[gdst[i]] = lsort[i];
}

// Fused degree-count + node scan + IN-PLACE node sort + f16 prescale.
// SPLIT: 2 half-blocks per bucket (grid 782). Each half reads the full
// bucket segment, counts all 256 degrees (identical totals; ranks are
// block-local and consistent with its own scatter), then sorts/flushes
// ONLY its 128 nodes: base = half ? wte[2] : 0 (from the scan for free).
__global__ __launch_bounds__(BTH) void k_build(int* __restrict__ binned,
                                               const int* __restrict__ gcursor,
                                               const float* __restrict__ x,
                                               int2* __restrict__ pse,
                                               _Float16* __restrict__ xs, int n) {
    __shared__ int cnt[KB];
    __shared__ int wt[4];
    __shared__ int wte[4];
    __shared__ int stage[HCAP];
    int tid = threadIdx.x;
    int lane = tid & 63, w = tid >> 6;
    int half = blockIdx.x & 1;
    int bkt = blockIdx.x >> 1;
    int beg = bkt * CAP;
    int tot = gcursor[bkt];                    // relative fill count
    if (tid < KB) cnt[tid] = 0;
    __syncthreads();
    int4 r[5];                                 // CAP/(BTH*4) = 5 max iters
    int4 rr[5];                                // per-edge rank within node
    #pragma unroll
    for (int it = 0; it < 5; ++it) {
        int j0 = (tid << 2) + it * (BTH * 4);
        if (j0 < tot) {
            r[it] = *(const int4*)(binned + beg + j0);
            rr[it].x = atomicAdd(&cnt[((unsigned)r[it].x) >> 24], 1);
            if (j0 + 1 < tot) rr[it].y = atomicAdd(&cnt[((unsigned)r[it].y) >> 24], 1);
            if (j0 + 2 < tot) rr[it].z = atomicAdd(&cnt[((unsigned)r[it].z) >> 24], 1);
            if (j0 + 3 < tot) rr[it].w = atomicAdd(&cnt[((unsigned)r[it].w) >> 24], 1);
        }
    }
    __syncthreads();
    // exclusive scan of 256 degrees (waves 0-3 carry tid<KB)
    int deg = (tid < KB) ? cnt[tid] : 0;
    int v = deg;
    #pragma unroll
    for (int m = 1; m < 64; m <<= 1) { int u = __shfl_up(v, m); if (lane >= m) v += u; }
    if (tid < KB && lane == 63) wt[w] = v;
    __syncthreads();
    if (tid == 0) {
        int s = 0;
        #pragma unroll
        for (int k = 0; k < 4; ++k) { wte[k] = s; s += wt[k]; }
    }
    __syncthreads();
    int obase = half ? wte[2] : 0;             // own half's flush base
    if (tid < KB) {
        int rel = wte[w] + v - deg;            // relative slot in bucket
        cnt[tid] = rel;                        // scatter base (constant now)
        if ((tid >> 7) == half) {              // own half writes pse/xs
            int node = bkt * KB + tid;
            pse[node] = make_int2(beg + rel, beg + rel + deg);
            float d = rsqrtf(1.0f + (float)deg);
            vh8 hq = {};
            if (node < n) {
                hq[0] = (_Float16)(x[node * IN_C + 0] * d);
                hq[1] = (_Float16)(x[node * IN_C + 1] * d);
                hq[2] = (_Float16)(x[node * IN_C + 2] * d);
                hq[3] = (_Float16)(x[node * IN_C + 3] * d);
                hq[4] = (_Float16)(x[node * IN_C + 4] * d);
                hq[5] = (_Float16)d;
            }
            *((vh8*)(xs + (size_t)node * 8)) = hq;
        }
    }
    __syncthreads();
    // atomic-free scatter of OWN-half edges: slot = cnt[node] + rank - obase
    #pragma unroll
    for (int it = 0; it < 5; ++it) {
        int j0 = (tid << 2) + it * (BTH * 4);
        if (j0 < tot) {
            int nd;
            nd = ((unsigned)r[it].x) >> 24;
            if ((nd >> 7) == half) stage[cnt[nd] + rr[it].x - obase] = r[it].x & 0xFFFFFF;
            if (j0 + 1 < tot) {
                nd = ((unsigned)r[it].y) >> 24;
                if ((nd >> 7) == half) stage[cnt[nd] + rr[it].y - obase] = r[it].y & 0xFFFFFF;
            }
            if (j0 + 2 < tot) {
                nd = ((unsigned)r[it].z) >> 24;
                if ((nd >> 7) == half) stage[cnt[nd] + rr[it].z - obase] = r[it].z & 0xFFFFFF;
            }
            if (j0 + 3 < tot) {
                nd = ((unsigned)r[it].w) >> 24;
                if ((nd >> 7) == half) stage[cnt[nd] + rr[it].w - obase] = r[it].w & 0xFFFFFF;
            }
        }
    }
    __syncthreads();
    // coalesced flush of own half: [beg+obase, beg+obase+otot)
    int otot = half ? (tot - wte[2]) : wte[2];
    for (int j = tid; j < otot; j += BTH)
        binned[beg + obase + j] = stage[j];
}

// Ahat pass 1, atomic-free: 8 threads/node, ONE 16B f16 load per edge.
// feat=xs -> outf=p1 (scale d^2; ch5 carries d), tout = d*a5 (rowsum).
__global__ __launch_bounds__(BTH) void k_gath0(const int* __restrict__ srclist,
                                               const int2* __restrict__ pse,
                                               const _Float16* __restrict__ feat,
                                               _Float16* __restrict__ outf,
                                               float* __restrict__ tout, int n) {
    int tid = threadIdx.x;
    int node = blockIdx.x * GNODES + (tid >> 3);
    int sub = tid & 7;
    if (node >= n) return;
    int2 pp = pse[node];
    int ps = pp.x, pe = pp.y;
    float a0 = 0, a1 = 0, a2 = 0, a3 = 0, a4 = 0, a5 = 0;
    int j = ps + sub;
    for (; j + 24 < pe; j += 32) {             // 4 edges/iter/thread
        int s0 = srclist[j],      s1 = srclist[j + 8];
        int s2 = srclist[j + 16], s3 = srclist[j + 24];
        vh8 h0 = *(const vh8*)(feat + (size_t)s0 * 8);
        vh8 h1 = *(const vh8*)(feat + (size_t)s1 * 8);
        vh8 h2 = *(const vh8*)(feat + (size_t)s2 * 8);
        vh8 h3 = *(const vh8*)(feat + (size_t)s3 * 8);
        a0 += ((float)h0[0] + (float)h1[0]) + ((float)h2[0] + (float)h3[0]);
        a1 += ((float)h0[1] + (float)h1[1]) + ((float)h2[1] + (float)h3[1]);
        a2 += ((float)h0[2] + (float)h1[2]) + ((float)h2[2] + (float)h3[2]);
        a3 += ((float)h0[3] + (float)h1[3]) + ((float)h2[3] + (float)h3[3]);
        a4 += ((float)h0[4] + (float)h1[4]) + ((float)h2[4] + (float)h3[4]);
        a5 += ((float)h0[5] + (float)h1[5]) + ((float)h2[5] + (float)h3[5]);
    }
    for (; j < pe; j += 8) {
        int sA = srclist[j];
        vh8 hA = *(const vh8*)(feat + (size_t)sA * 8);
        a0 += (float)hA[0]; a1 += (float)hA[1]; a2 += (float)hA[2];
        a3 += (float)hA[3]; a4 += (float)hA[4]; a5 += (float)hA[5];
    }
    #pragma unroll
    for (int m = 1; m < 8; m <<= 1) {
        a0 += __shfl_xor(a0, m);
        a1 += __shfl_xor(a1, m);
        a2 += __shfl_xor(a2, m);
        a3 += __shfl_xor(a3, m);
        a4 += __shfl_xor(a4, m);
        a5 += __shfl_xor(a5, m);
    }
    if (sub == 0) {
        vh8 hs = *(const vh8*)(feat + (size_t)node * 8);
        float d = (float)hs[5];
        a0 += (float)hs[0]; a1 += (float)hs[1]; a2 += (float)hs[2];
        a3 += (float)hs[3]; a4 += (float)hs[4]; a5 += d;
        float d2 = d * d;
        vh8 ho = {};
        ho[0] = (_Float16)(d2 * a0);
        ho[1] = (_Float16)(d2 * a1);
        ho[2] = (_Float16)(d2 * a2);
        ho[3] = (_Float16)(d2 * a3);
        ho[4] = (_Float16)(d2 * a4);
        ho[5] = (_Float16)d;                   // carry d forward
        tout[node] = d * a5;                   // rowsum of Ahat
        *((vh8*)(outf + (size_t)node * 8)) = ho;
    }
}

// Fused Ahat pass 2 + weight fold + output projection (8 thr/node).
__global__ __launch_bounds__(BTH) void k_gout(const int* __restrict__ srclist,
                                              const int2* __restrict__ pse,
                                              const _Float16* __restrict__ feat,
                                              const float* __restrict__ t,
                                              const float* __restrict__ W1,
                                              const float* __restrict__ b1,
                                              const float* __restrict__ W2,
                                              const float* __restrict__ b2,
                                              float* __restrict__ out, int n) {
    __shared__ float snode[GNODES * 8];    // a0..a4, t  (stride 8)
    __shared__ float sW[IN_C * OUT_C + 2 * OUT_C];   // Wc | bc | b2
    int tid = threadIdx.x;
    // in-block weight fold: Wc = W1@W2, bc = b1@W2 (W2 is L2-resident)
    if (tid < IN_C * OUT_C) {
        int k = tid >> 6, c = tid & 63;
        float acc = 0.0f;
        for (int m = 0; m < HID_C; ++m)
            acc += W1[k * HID_C + m] * W2[m * OUT_C + c];
        sW[tid] = acc;
    } else if (tid < IN_C * OUT_C + OUT_C) {
        int c = tid - IN_C * OUT_C;
        float acc = 0.0f;
        for (int m = 0; m < HID_C; ++m)
            acc += b1[m] * W2[m * OUT_C + c];
        sW[tid] = acc;
    } else if (tid < IN_C * OUT_C + 2 * OUT_C) {
        sW[tid] = b2[tid - IN_C * OUT_C - OUT_C];
    }
    int node = blockIdx.x * GNODES + (tid >> 3);
    int sub = tid & 7;
    bool act = (node < n);
    float a0 = 0, a1 = 0, a2 = 0, a3 = 0, a4 = 0;
    if (act) {
        int2 pp = pse[node];
        int ps = pp.x, pe = pp.y;
        int j = ps + sub;
        for (; j + 24 < pe; j += 32) {         // 4 edges/iter/thread
            int s0 = srclist[j],      s1 = srclist[j + 8];
            int s2 = srclist[j + 16], s3 = srclist[j + 24];
            vh8 h0 = *(const vh8*)(feat + (size_t)s0 * 8);
            vh8 h1 = *(const vh8*)(feat + (size_t)s1 * 8);
            vh8 h2 = *(const vh8*)(feat + (size_t)s2 * 8);
            vh8 h3 = *(const vh8*)(feat + (size_t)s3 * 8);
            a0 += ((float)h0[0] + (float)h1[0]) + ((float)h2[0] + (float)h3[0]);
            a1 += ((float)h0[1] + (float)h1[1]) + ((float)h2[1] + (float)h3[1]);
            a2 += ((float)h0[2] + (float)h1[2]) + ((float)h2[2] + (float)h3[2]);
            a3 += ((float)h0[3] + (float)h1[3]) + ((float)h2[3] + (float)h3[3]);
            a4 += ((float)h0[4] + (float)h1[4]) + ((float)h2[4] + (float)h3[4]);
        }
        for (; j < pe; j += 8) {
            int sA = srclist[j];
            vh8 hA = *(const vh8*)(feat + (size_t)sA * 8);
            a0 += (float)hA[0]; a1 += (float)hA[1]; a2 += (float)hA[2];
            a3 += (float)hA[3]; a4 += (float)hA[4];
        }
    }
    #pragma unroll
    for (int m = 1; m < 8; m <<= 1) {
        a0 += __shfl_xor(a0, m);
        a1 += __shfl_xor(a1, m);
        a2 += __shfl_xor(a2, m);
        a3 += __shfl_xor(a3, m);
        a4 += __shfl_xor(a4, m);
    }
    if (act && sub == 0) {
        vh8 hs = *(const vh8*)(feat + (size_t)node * 8);
        float d = (float)hs[5];
        a0 += (float)hs[0]; a1 += (float)hs[1]; a2 += (float)hs[2];
        a3 += (float)hs[3]; a4 += (float)hs[4];
        float* sn = snode + (tid >> 3) * 8;
        sn[0] = d * a0; sn[1] = d * a1; sn[2] = d * a2;
        sn[3] = d * a3; sn[4] = d * a4; sn[5] = t[node];
    }
    __syncthreads();
    // expand: 64 nodes x 16 float4 channels = 1024 float4 / block
    int base = blockIdx.x * GNODES;
    for (int u = tid; u < GNODES * 16; u += BTH) {
        int ln = u >> 4, q = u & 15;
        int i = base + ln;
        if (i >= n) continue;
        const float* a = snode + ln * 8;
        float ti = a[5];
        float4 acc = ((const float4*)(sW + IN_C * OUT_C + OUT_C))[q];   // b2
        float4 bq  = ((const float4*)(sW + IN_C * OUT_C))[q];           // bc
        acc.x += ti * bq.x; acc.y += ti * bq.y;
        acc.z += ti * bq.z; acc.w += ti * bq.w;
        #pragma unroll
        for (int k = 0; k < IN_C; ++k) {
            float ak = a[k];
            float4 wk = ((const float4*)(sW + k * OUT_C))[q];
            acc.x += ak * wk.x; acc.y += ak * wk.y;
            acc.z += ak * wk.z; acc.w += ak * wk.w;
        }
        vf4 av; av.x = acc.x; av.y = acc.y; av.z = acc.z; av.w = acc.w;
        __builtin_nontemporal_store(av, ((vf4*)out) + (size_t)i * 16 + q);
    }
}

extern "C" void kernel_launch(void* const* d_in, const int* in_sizes, int n_in,
                              void* d_out, int out_size, void* d_ws, size_t ws_size,
                              hipStream_t stream) {
    const float* x   = (const float*)d_in[0];
    const int*   ei  = (const int*)d_in[1];
    const float* W1  = (const float*)d_in[2];
    const float* b1  = (const float*)d_in[3];
    const float* W2  = (const float*)d_in[4];
    const float* b2  = (const float*)d_in[5];
    float* out = (float*)d_out;

    const int n = in_sizes[0] / IN_C;       // 100000
    const int e = in_sizes[1] / 2;          // 3200000
    const int* src = ei;
    const int* dst = ei + e;
    const int NB = (n + KB - 1) / KB;       // 391
    const int NKB = NB * KB;                // 100096

    // Workspace layout (segments 16B-aligned)
    int*      gcursor = (int*)d_ws;                       // 512 (relative fills)
    int*      binned  = gcursor + 512;                    // NBP*CAP (in-place srclist)
    int2*     pse     = (int2*)(binned + (size_t)NBP * CAP); // NKB int2
    _Float16* xs      = (_Float16*)(pse + NKB);           // 8 halves * NKB (16B/node)
    _Float16* p1      = xs + (size_t)8 * NKB;             // 8 halves * NKB
    float*    t       = (float*)(p1 + (size_t)8 * NKB);   // NKB floats

    const int gB = (e + TILE - 1) / TILE;           // 391
    const int gG = (n + GNODES - 1) / GNODES;       // 1563

    (void)hipMemsetAsync(gcursor, 0, NBP * sizeof(int), stream);
    k_bin   <<<gB, BTH, 0, stream>>>(src, dst, gcursor, binned, e);
    k_build <<<NB * 2, BTH, 0, stream>>>(binned, gcursor, x, pse, xs, n);
    k_gath0 <<<gG, BTH, 0, stream>>>(binned, pse, xs, p1, t, n);
    k_gout  <<<gG, BTH, 0, stream>>>(binned, pse, p1, t,
                                     W1, b1, W2, b2, out, n);
}

// Round 14
// 165.372 us; speedup vs baseline: 1.0302x; 1.0302x over previous
//
#include <hip/hip_runtime.h>

#define IN_C  5
#define HID_C 128
#define OUT_C 64

#define KB   256      // nodes per bucket (dst >> 8)
#define NBP  512      // padded bucket count (== BTH, one bucket per thread in scan)
#define CAP  10240    // fixed per-bucket edge capacity (mean 8184, +22 sigma)
#define TILE 8192     // edges per k_bin block (R21: 16-edge runs = full-line stores)
#define BTH  512      // block size
#define EPT  (TILE / BTH)
#define EPTV (TILE / BTH / 4)
#define GNODES 64     // nodes per gather block (8 threads/node x 512)

// Native vector types (__builtin_nontemporal_* rejects HIP_vector_type)
typedef int      vi4 __attribute__((ext_vector_type(4)));
typedef float    vf4 __attribute__((ext_vector_type(4)));
typedef _Float16 vh8 __attribute__((ext_vector_type(8)));

// ---------------------------------------------------------------------------
// Linear-GCN folding: z = Ahat^2 X (W1 W2) + (Ahat 1)(b1 W2) + b2.
// R25 = exact revert to R21 (verified 166.3us, best of session).
// Falsified variants: R22 padded int4-srclist (+3.6), R24 split k_build
// (+4.1), R20 global deg atomics (+130), R16 nt srclist (+16), R14 direct
// scatter (+8), R19/R20 fused per-bucket gathers (neutral).
// Ceiling model: gathers MSHR-bound (~0.147 miss/cy/CU = 30 MSHRs x 200cy
// L2 latency; only lookup COUNT moves it, at 1/edge minimum since R18 f16
// 16B records). Partition bound by 2x global round-trip + LDS sort of 3.2M
// edges. ~166us = gathers ~78 + partition ~69 + launch/tail ~10.
// Payload packed 4B: (dst&255)<<24 | src; payload may be NEGATIVE when
// (dst&255)>=128 — never sign-test validity (R4 bug).
// ---------------------------------------------------------------------------

// Bucket-partition a tile: LDS hist (rank-capturing) -> scan -> bucket-sorted
// LDS stage with precomputed global dests -> run-contiguous global stores.
__global__ __launch_bounds__(BTH) void k_bin(const int* __restrict__ src,
                                             const int* __restrict__ dstp,
                                             int* __restrict__ gcursor,
                                             int* __restrict__ binned, int e) {
    __shared__ int lhist[NBP];
    __shared__ int lgofs[NBP];    // (bucket global window) - (local run start)
    __shared__ int lbeg[NBP];
    __shared__ int lsort[TILE];
    __shared__ int gdst[TILE];
    __shared__ int wsum[8];
    __shared__ int stot;
    int tid = threadIdx.x;
    int lane = tid & 63, w = tid >> 6;
    int tbeg = blockIdx.x * TILE;
    lhist[tid] = 0;                            // NBP == BTH
    __syncthreads();
    int pk[EPT], bk[EPT], rk[EPT];
    #pragma unroll
    for (int q = 0; q < EPTV; ++q) {
        int idx = tbeg + (q * BTH + tid) * 4;  // e % 4 == 0: all-or-nothing
        if (idx < e) {
            vi4 s4 = __builtin_nontemporal_load((const vi4*)(src + idx));
            vi4 d4 = __builtin_nontemporal_load((const vi4*)(dstp + idx));
            pk[q*4+0] = ((d4.x & 255) << 24) | s4.x; bk[q*4+0] = ((unsigned)d4.x) >> 8;
            pk[q*4+1] = ((d4.y & 255) << 24) | s4.y; bk[q*4+1] = ((unsigned)d4.y) >> 8;
            pk[q*4+2] = ((d4.z & 255) << 24) | s4.z; bk[q*4+2] = ((unsigned)d4.z) >> 8;
            pk[q*4+3] = ((d4.w & 255) << 24) | s4.w; bk[q*4+3] = ((unsigned)d4.w) >> 8;
            rk[q*4+0] = atomicAdd(&lhist[bk[q*4+0]], 1);   // rank in bucket
            rk[q*4+1] = atomicAdd(&lhist[bk[q*4+1]], 1);
            rk[q*4+2] = atomicAdd(&lhist[bk[q*4+2]], 1);
            rk[q*4+3] = atomicAdd(&lhist[bk[q*4+3]], 1);
        } else {
            bk[q*4+0] = -1; bk[q*4+1] = -1; bk[q*4+2] = -1; bk[q*4+3] = -1;
        }
    }
    __syncthreads();
    // block-wide exclusive scan of 512 bucket counts (one per thread)
    int h = lhist[tid];
    int v = h;
    #pragma unroll
    for (int m = 1; m < 64; m <<= 1) { int u = __shfl_up(v, m); if (lane >= m) v += u; }
    if (lane == 63) wsum[w] = v;
    __syncthreads();
    if (tid == 0) {
        int s = 0;
        #pragma unroll
        for (int k = 0; k < 8; ++k) { int tv = wsum[k]; wsum[k] = s; s += tv; }
    }
    __syncthreads();
    int excl = wsum[w] + v - h;                // exclusive prefix for bucket tid
    lbeg[tid] = excl;
    if (h > 0)
        lgofs[tid] = tid * CAP + atomicAdd(&gcursor[tid], h) - excl;
    if (tid == BTH - 1) stot = excl + h;       // total valid edges in tile
    __syncthreads();
    #pragma unroll
    for (int q = 0; q < EPT; ++q) {
        if (bk[q] >= 0) {
            int slot = lbeg[bk[q]] + rk[q];    // no second atomic
            lsort[slot] = pk[q];
            gdst[slot] = lgofs[bk[q]] + slot;  // consecutive within a run
        }
    }
    __syncthreads();
    int tot = stot;
    for (int i = tid; i < tot; i += BTH)
        binned[gdst[i]] = lsort[i];
}

// Fused degree-count + node scan + IN-PLACE node sort + f16 feature prescale.
// Pass 1: count degrees, capture per-edge rank from atomicAdd return;
// edges stay register-cached (<=5 int4/thr). Pass 2: atomic-free scatter
// (slot = excl[node] + rank) into LDS stage, coalesced flush in place.
__global__ __launch_bounds__(BTH) void k_build(int* __restrict__ binned,
                                               const int* __restrict__ gcursor,
                                               const float* __restrict__ x,
                                               int2* __restrict__ pse,
                                               _Float16* __restrict__ xs, int n) {
    __shared__ int cnt[KB];
    __shared__ int wt[4];
    __shared__ int wte[4];
    __shared__ int stage[CAP];
    int tid = threadIdx.x;
    int lane = tid & 63, w = tid >> 6;
    int bkt = blockIdx.x;
    int beg = bkt * CAP;
    int tot = gcursor[bkt];                    // relative fill count
    if (tid < KB) cnt[tid] = 0;
    __syncthreads();
    int4 r[5];                                 // CAP/(BTH*4) = 5 max iters
    int4 rr[5];                                // per-edge rank within node
    #pragma unroll
    for (int it = 0; it < 5; ++it) {
        int j0 = (tid << 2) + it * (BTH * 4);
        if (j0 < tot) {
            r[it] = *(const int4*)(binned + beg + j0);
            rr[it].x = atomicAdd(&cnt[((unsigned)r[it].x) >> 24], 1);
            if (j0 + 1 < tot) rr[it].y = atomicAdd(&cnt[((unsigned)r[it].y) >> 24], 1);
            if (j0 + 2 < tot) rr[it].z = atomicAdd(&cnt[((unsigned)r[it].z) >> 24], 1);
            if (j0 + 3 < tot) rr[it].w = atomicAdd(&cnt[((unsigned)r[it].w) >> 24], 1);
        }
    }
    __syncthreads();
    // exclusive scan of 256 degrees (waves 0-3 carry tid<KB)
    int deg = (tid < KB) ? cnt[tid] : 0;
    int v = deg;
    #pragma unroll
    for (int m = 1; m < 64; m <<= 1) { int u = __shfl_up(v, m); if (lane >= m) v += u; }
    if (tid < KB && lane == 63) wt[w] = v;
    __syncthreads();
    if (tid == 0) {
        int s = 0;
        #pragma unroll
        for (int k = 0; k < 4; ++k) { wte[k] = s; s += wt[k]; }
    }
    __syncthreads();
    if (tid < KB) {
        int rel = wte[w] + v - deg;            // relative slot in bucket
        int node = bkt * KB + tid;
        pse[node] = make_int2(beg + rel, beg + rel + deg);
        cnt[tid] = rel;                        // exclusive start (constant now)
        float d = rsqrtf(1.0f + (float)deg);
        vh8 hq = {};
        if (node < n) {
            hq[0] = (_Float16)(x[node * IN_C + 0] * d);
            hq[1] = (_Float16)(x[node * IN_C + 1] * d);
            hq[2] = (_Float16)(x[node * IN_C + 2] * d);
            hq[3] = (_Float16)(x[node * IN_C + 3] * d);
            hq[4] = (_Float16)(x[node * IN_C + 4] * d);
            hq[5] = (_Float16)d;
        }
        *((vh8*)(xs + (size_t)node * 8)) = hq;
    }
    __syncthreads();
    // atomic-free scatter: slot = cnt[node] + rank (plain LDS read + write)
    #pragma unroll
    for (int it = 0; it < 5; ++it) {
        int j0 = (tid << 2) + it * (BTH * 4);
        if (j0 < tot) {
            stage[cnt[((unsigned)r[it].x) >> 24] + rr[it].x] = r[it].x & 0xFFFFFF;
            if (j0 + 1 < tot)
                stage[cnt[((unsigned)r[it].y) >> 24] + rr[it].y] = r[it].y & 0xFFFFFF;
            if (j0 + 2 < tot)
                stage[cnt[((unsigned)r[it].z) >> 24] + rr[it].z] = r[it].z & 0xFFFFFF;
            if (j0 + 3 < tot)
                stage[cnt[((unsigned)r[it].w) >> 24] + rr[it].w] = r[it].w & 0xFFFFFF;
        }
    }
    __syncthreads();
    // in-place COALESCED flush: binned segment becomes node-contiguous srclist
    for (int j = tid; j < tot; j += BTH)
        binned[beg + j] = stage[j];
}

// Ahat pass 1, atomic-free: 8 threads/node, ONE 16B f16 load per edge.
// feat=xs -> outf=p1 (scale d^2; ch5 carries d), tout = d*a5 (rowsum).
__global__ __launch_bounds__(BTH) void k_gath0(const int* __restrict__ srclist,
                                               const int2* __restrict__ pse,
                                               const _Float16* __restrict__ feat,
                                               _Float16* __restrict__ outf,
                                               float* __restrict__ tout, int n) {
    int tid = threadIdx.x;
    int node = blockIdx.x * GNODES + (tid >> 3);
    int sub = tid & 7;
    if (node >= n) return;
    int2 pp = pse[node];
    int ps = pp.x, pe = pp.y;
    float a0 = 0, a1 = 0, a2 = 0, a3 = 0, a4 = 0, a5 = 0;
    int j = ps + sub;
    for (; j + 24 < pe; j += 32) {             // 4 edges/iter/thread
        int s0 = srclist[j],      s1 = srclist[j + 8];
        int s2 = srclist[j + 16], s3 = srclist[j + 24];
        vh8 h0 = *(const vh8*)(feat + (size_t)s0 * 8);
        vh8 h1 = *(const vh8*)(feat + (size_t)s1 * 8);
        vh8 h2 = *(const vh8*)(feat + (size_t)s2 * 8);
        vh8 h3 = *(const vh8*)(feat + (size_t)s3 * 8);
        a0 += ((float)h0[0] + (float)h1[0]) + ((float)h2[0] + (float)h3[0]);
        a1 += ((float)h0[1] + (float)h1[1]) + ((float)h2[1] + (float)h3[1]);
        a2 += ((float)h0[2] + (float)h1[2]) + ((float)h2[2] + (float)h3[2]);
        a3 += ((float)h0[3] + (float)h1[3]) + ((float)h2[3] + (float)h3[3]);
        a4 += ((float)h0[4] + (float)h1[4]) + ((float)h2[4] + (float)h3[4]);
        a5 += ((float)h0[5] + (float)h1[5]) + ((float)h2[5] + (float)h3[5]);
    }
    for (; j < pe; j += 8) {
        int sA = srclist[j];
        vh8 hA = *(const vh8*)(feat + (size_t)sA * 8);
        a0 += (float)hA[0]; a1 += (float)hA[1]; a2 += (float)hA[2];
        a3 += (float)hA[3]; a4 += (float)hA[4]; a5 += (float)hA[5];
    }
    #pragma unroll
    for (int m = 1; m < 8; m <<= 1) {
        a0 += __shfl_xor(a0, m);
        a1 += __shfl_xor(a1, m);
        a2 += __shfl_xor(a2, m);
        a3 += __shfl_xor(a3, m);
        a4 += __shfl_xor(a4, m);
        a5 += __shfl_xor(a5, m);
    }
    if (sub == 0) {
        vh8 hs = *(const vh8*)(feat + (size_t)node * 8);
        float d = (float)hs[5];
        a0 += (float)hs[0]; a1 += (float)hs[1]; a2 += (float)hs[2];
        a3 += (float)hs[3]; a4 += (float)hs[4]; a5 += d;
        float d2 = d * d;
        vh8 ho = {};
        ho[0] = (_Float16)(d2 * a0);
        ho[1] = (_Float16)(d2 * a1);
        ho[2] = (_Float16)(d2 * a2);
        ho[3] = (_Float16)(d2 * a3);
        ho[4] = (_Float16)(d2 * a4);
        ho[5] = (_Float16)d;                   // carry d forward
        tout[node] = d * a5;                   // rowsum of Ahat
        *((vh8*)(outf + (size_t)node * 8)) = ho;
    }
}

// Fused Ahat pass 2 + weight fold + output projection (8 thr/node).
__global__ __launch_bounds__(BTH) void k_gout(const int* __restrict__ srclist,
                                              const int2* __restrict__ pse,
                                              const _Float16* __restrict__ feat,
                                              const float* __restrict__ t,
                                              const float* __restrict__ W1,
                                              const float* __restrict__ b1,
                                              const float* __restrict__ W2,
                                              const float* __restrict__ b2,
                                              float* __restrict__ out, int n) {
    __shared__ float snode[GNODES * 8];    // a0..a4, t  (stride 8)
    __shared__ float sW[IN_C * OUT_C + 2 * OUT_C];   // Wc | bc | b2
    int tid = threadIdx.x;
    // in-block weight fold: Wc = W1@W2, bc = b1@W2 (W2 is L2-resident)
    if (tid < IN_C * OUT_C) {
        int k = tid >> 6, c = tid & 63;
        float acc = 0.0f;
        for (int m = 0; m < HID_C; ++m)
            acc += W1[k * HID_C + m] * W2[m * OUT_C + c];
        sW[tid] = acc;
    } else if (tid < IN_C * OUT_C + OUT_C) {
        int c = tid - IN_C * OUT_C;
        float acc = 0.0f;
        for (int m = 0; m < HID_C; ++m)
            acc += b1[m] * W2[m * OUT_C + c];
        sW[tid] = acc;
    } else if (tid < IN_C * OUT_C + 2 * OUT_C) {
        sW[tid] = b2[tid - IN_C * OUT_C - OUT_C];
    }
    int node = blockIdx.x * GNODES + (tid >> 3);
    int sub = tid & 7;
    bool act = (node < n);
    float a0 = 0, a1 = 0, a2 = 0, a3 = 0, a4 = 0;
    if (act) {
        int2 pp = pse[node];
        int ps = pp.x, pe = pp.y;
        int j = ps + sub;
        for (; j + 24 < pe; j += 32) {         // 4 edges/iter/thread
            int s0 = srclist[j],      s1 = srclist[j + 8];
            int s2 = srclist[j + 16], s3 = srclist[j + 24];
            vh8 h0 = *(const vh8*)(feat + (size_t)s0 * 8);
            vh8 h1 = *(const vh8*)(feat + (size_t)s1 * 8);
            vh8 h2 = *(const vh8*)(feat + (size_t)s2 * 8);
            vh8 h3 = *(const vh8*)(feat + (size_t)s3 * 8);
            a0 += ((float)h0[0] + (float)h1[0]) + ((float)h2[0] + (float)h3[0]);
            a1 += ((float)h0[1] + (float)h1[1]) + ((float)h2[1] + (float)h3[1]);
            a2 += ((float)h0[2] + (float)h1[2]) + ((float)h2[2] + (float)h3[2]);
            a3 += ((float)h0[3] + (float)h1[3]) + ((float)h2[3] + (float)h3[3]);
            a4 += ((float)h0[4] + (float)h1[4]) + ((float)h2[4] + (float)h3[4]);
        }
        for (; j < pe; j += 8) {
            int sA = srclist[j];
            vh8 hA = *(const vh8*)(feat + (size_t)sA * 8);
            a0 += (float)hA[0]; a1 += (float)hA[1]; a2 += (float)hA[2];
            a3 += (float)hA[3]; a4 += (float)hA[4];
        }
    }
    #pragma unroll
    for (int m = 1; m < 8; m <<= 1) {
        a0 += __shfl_xor(a0, m);
        a1 += __shfl_xor(a1, m);
        a2 += __shfl_xor(a2, m);
        a3 += __shfl_xor(a3, m);
        a4 += __shfl_xor(a4, m);
    }
    if (act && sub == 0) {
        vh8 hs = *(const vh8*)(feat + (size_t)node * 8);
        float d = (float)hs[5];
        a0 += (float)hs[0]; a1 += (float)hs[1]; a2 += (float)hs[2];
        a3 += (float)hs[3]; a4 += (float)hs[4];
        float* sn = snode + (tid >> 3) * 8;
        sn[0] = d * a0; sn[1] = d * a1; sn[2] = d * a2;
        sn[3] = d * a3; sn[4] = d * a4; sn[5] = t[node];
    }
    __syncthreads();
    // expand: 64 nodes x 16 float4 channels = 1024 float4 / block
    int base = blockIdx.x * GNODES;
    for (int u = tid; u < GNODES * 16; u += BTH) {
        int ln = u >> 4, q = u & 15;
        int i = base + ln;
        if (i >= n) continue;
        const float* a = snode + ln * 8;
        float ti = a[5];
        float4 acc = ((const float4*)(sW + IN_C * OUT_C + OUT_C))[q];   // b2
        float4 bq  = ((const float4*)(sW + IN_C * OUT_C))[q];           // bc
        acc.x += ti * bq.x; acc.y += ti * bq.y;
        acc.z += ti * bq.z; acc.w += ti * bq.w;
        #pragma unroll
        for (int k = 0; k < IN_C; ++k) {
            float ak = a[k];
            float4 wk = ((const float4*)(sW + k * OUT_C))[q];
            acc.x += ak * wk.x; acc.y += ak * wk.y;
            acc.z += ak * wk.z; acc.w += ak * wk.w;
        }
        vf4 av; av.x = acc.x; av.y = acc.y; av.z = acc.z; av.w = acc.w;
        __builtin_nontemporal_store(av, ((vf4*)out) + (size_t)i * 16 + q);
    }
}

extern "C" void kernel_launch(void* const* d_in, const int* in_sizes, int n_in,
                              void* d_out, int out_size, void* d_ws, size_t ws_size,
                              hipStream_t stream) {
    const float* x   = (const float*)d_in[0];
    const int*   ei  = (const int*)d_in[1];
    const float* W1  = (const float*)d_in[2];
    const float* b1  = (const float*)d_in[3];
    const float* W2  = (const float*)d_in[4];
    const float* b2  = (const float*)d_in[5];
    float* out = (float*)d_out;

    const int n = in_sizes[0] / IN_C;       // 100000
    const int e = in_sizes[1] / 2;          // 3200000
    const int* src = ei;
    const int* dst = ei + e;
    const int NB = (n + KB - 1) / KB;       // 391
    const int NKB = NB * KB;                // 100096

    // Workspace layout (segments 16B-aligned)
    int*      gcursor = (int*)d_ws;                       // 512 (relative fills)
    int*      binned  = gcursor + 512;                    // NBP*CAP (in-place srclist)
    int2*     pse     = (int2*)(binned + (size_t)NBP * CAP); // NKB int2
    _Float16* xs      = (_Float16*)(pse + NKB);           // 8 halves * NKB (16B/node)
    _Float16* p1      = xs + (size_t)8 * NKB;             // 8 halves * NKB
    float*    t       = (float*)(p1 + (size_t)8 * NKB);   // NKB floats

    const int gB = (e + TILE - 1) / TILE;           // 391
    const int gG = (n + GNODES - 1) / GNODES;       // 1563

    (void)hipMemsetAsync(gcursor, 0, NBP * sizeof(int), stream);
    k_bin   <<<gB, BTH, 0, stream>>>(src, dst, gcursor, binned, e);
    k_build <<<NB, BTH, 0, stream>>>(binned, gcursor, x, pse, xs, n);
    k_gath0 <<<gG, BTH, 0, stream>>>(binned, pse, xs, p1, t, n);
    k_gout  <<<gG, BTH, 0, stream>>>(binned, pse, p1, t,
                                     W1, b1, W2, b2, out, n);
}